// Round 13
// baseline (426.135 us; speedup 1.0000x reference)
//
#include <hip/hip_runtime.h>
#include <hip/hip_bf16.h>
#include <hip/hip_fp16.h>

// Decoder_22273700397282 on MI355X (gfx950)
// out[b,f] = trigger_a[b,f] * sum_t softmax_f(tanh(a@Wa + ba + s@Ws + bs))[t,f]
// mask==0 rows -> exactly 1/3072 per feature (handled analytically).
//
// R13: k_gemm barrier halving — workgroup barrier only after even phases
// (4 per 2 K-tiles instead of 8). Slot schedule unchanged. Verified:
// within each unsynced phase-pair the read-region and stage-region are
// disjoint LDS buffers; WAR across pairs separated by the pair-end barrier;
// vmcnt(4)@ph4/ph8 certifies each slot >=1 barrier before its read.
// Also: k_sum_h vectorized to float4.

namespace {
constexpr int SIN  = 1024;            // IN_SIZE
constexpr int KH   = 2048;            // 2*IN
constexpr int NF   = 3072;            // 3*IN = GEMM K and N
constexpr int NBAT = 32;
constexpr int NS   = 512;
constexpr int NM   = NBAT * NS;       // 16384 worst-case GEMM rows
constexpr int NDB  = NF / 64;         // 48 Dpart column blocks
constexpr int KC   = 8;               // k-chunks for k_base1
constexpr int NKT  = NF / 64;         // 48 K-tiles of 64
constexpr int NCH  = 8;               // 64-row chunks per batch
}

typedef unsigned short u16;
typedef __bf16 bf16x8 __attribute__((ext_vector_type(8)));
typedef float  f32x4  __attribute__((ext_vector_type(4)));

#define ASYNC_CP16(gptr, lptr)                                                              \
  __builtin_amdgcn_global_load_lds((__attribute__((address_space(1))) void*)(gptr),         \
                                   (__attribute__((address_space(3))) void*)(lptr), 16, 0, 0)

__device__ __forceinline__ u16 f2b(float f) {
  union { float f; unsigned u; } v; v.f = f;
  unsigned u = v.u;
  u += 0x7FFFu + ((u >> 16) & 1u);     // round-to-nearest-even
  return (u16)(u >> 16);
}

// ---------------- prep: per-batch counts + scan + meta (one block) -------
__global__ __launch_bounds__(256) void k_prep(const int* __restrict__ mask,
                                              int* __restrict__ bcnt,
                                              int* __restrict__ boff,
                                              int* __restrict__ meta) {
  int tid = threadIdx.x;
  int b = tid >> 3, seg = tid & 7;                 // 8 threads per batch
  int c = 0;
#pragma unroll
  for (int i = 0; i < 64; ++i) c += mask[b * NS + seg * 64 + i];
  c += __shfl_xor(c, 1, 64);
  c += __shfl_xor(c, 2, 64);
  c += __shfl_xor(c, 4, 64);                       // 8-lane group total
  __shared__ int sc[NBAT];
  if (seg == 0) { sc[b] = c; bcnt[b] = c; }
  __syncthreads();
  if (tid == 0) {
    int run = 0;
    for (int bb = 0; bb < NBAT; ++bb) { boff[bb] = run; run += sc[bb]; }
    meta[0] = run;                       // Mc
    meta[1] = (run + 255) & ~255;        // McPad (256-row tiles)
  }
}

// ---------------- compaction: gather ----------------
__global__ __launch_bounds__(512) void k_gather(const int* __restrict__ mask,
                                                const int* __restrict__ boff,
                                                const int* __restrict__ meta,
                                                int* __restrict__ rowmap) {
  __shared__ int ps[NS];
  int b = blockIdx.x, t = threadIdx.x;
  int m = mask[b * NS + t];
  ps[t] = m;
  __syncthreads();
#pragma unroll
  for (int off = 1; off < NS; off <<= 1) {
    int v = (t >= off) ? ps[t - off] : 0;
    __syncthreads();
    ps[t] += v;
    __syncthreads();
  }
  if (m) rowmap[boff[b] + ps[t] - m] = b * NS + t;
  if (b == 0) {                          // zero-pad rowmap up to McPad
    int Mc = meta[0], McPad = meta[1];
    if (Mc + t < McPad) rowmap[Mc + t] = 0;
  }
}

// ---------------- s[b,k] = sum_t h[b,t,k] (float4) ----------------
__global__ __launch_bounds__(256) void k_sum_h(const float* __restrict__ h,
                                               float* __restrict__ s) {
  int b = blockIdx.x;
  int d = (blockIdx.y * 256 + threadIdx.x) * 4;    // 2 blocks.y cover 2048
  const float* p = h + (size_t)b * NS * KH + d;
  float4 acc = {0.f, 0.f, 0.f, 0.f};
#pragma unroll 4
  for (int t = 0; t < NS; ++t) {
    float4 v = *(const float4*)(p + (size_t)t * KH);
    acc.x += v.x; acc.y += v.y; acc.z += v.z; acc.w += v.w;
  }
  *(float4*)(s + b * KH + d) = acc;
}

// ---------------- base partials: reads Ws once; float4 LDS reads ---------
__global__ __launch_bounds__(256) void k_base1(const float* __restrict__ s,
                                               const float* __restrict__ Ws,
                                               float* __restrict__ basep) {
  __shared__ float sT[NBAT][KH / KC];      // [32][256] = 32 KB
  int f  = blockIdx.x * 256 + threadIdx.x;
  int k0 = blockIdx.y * (KH / KC);
  for (int it = 0; it < NBAT; ++it) {
    int idx = it * 256 + threadIdx.x;
    int b = idx >> 8, kk = idx & 255;
    sT[b][kk] = s[b * KH + k0 + kk];
  }
  __syncthreads();
  float acc[NBAT] = {};
  for (int k = 0; k < KH / KC; k += 4) {
    float w0 = Ws[(size_t)(k0 + k + 0) * NF + f];
    float w1 = Ws[(size_t)(k0 + k + 1) * NF + f];
    float w2 = Ws[(size_t)(k0 + k + 2) * NF + f];
    float w3 = Ws[(size_t)(k0 + k + 3) * NF + f];
#pragma unroll
    for (int b = 0; b < NBAT; ++b) {
      float4 sv = *(const float4*)&sT[b][k];
      acc[b] += sv.x * w0 + sv.y * w1 + sv.z * w2 + sv.w * w3;
    }
  }
#pragma unroll
  for (int b = 0; b < NBAT; ++b)
    basep[((size_t)blockIdx.y * NBAT + b) * NF + f] = acc[b];
}

__global__ __launch_bounds__(256) void k_base2(const float* __restrict__ basep,
                                               const float* __restrict__ ba,
                                               const float* __restrict__ bs,
                                               float* __restrict__ base) {
  int b = blockIdx.x;
  int f = blockIdx.y * 256 + threadIdx.x;
  float acc = 0.f;
#pragma unroll
  for (int kc = 0; kc < KC; ++kc) acc += basep[((size_t)kc * NBAT + b) * NF + f];
  base[b * NF + f] = acc + ba[f] + bs[f];
}

// ---------------- Abf[i,k] = bf16(concat(h,x)[rowmap[i],k]) --------------
__global__ __launch_bounds__(256) void k_cvt_a(const float* __restrict__ h,
                                               const float* __restrict__ x,
                                               const int* __restrict__ rowmap,
                                               const int* __restrict__ meta,
                                               u16* __restrict__ A) {
  const int total = meta[1] * (NF / 4);
  for (int idx = blockIdx.x * 256 + threadIdx.x; idx < total;
       idx += gridDim.x * 256) {
    int i = idx / (NF / 4);
    int k = (idx - i * (NF / 4)) * 4;
    ushort4 o;
    if (i >= meta[0]) {
      o.x = o.y = o.z = o.w = 0;
    } else {
      int ro = rowmap[i];
      int b = ro >> 9, t = ro & 511;
      const float* src = (k < KH) ? h + ((size_t)b * NS + t) * KH + k
                                  : x + ((size_t)b * NS + t) * SIN + (k - KH);
      float4 v = *(const float4*)src;
      o.x = f2b(v.x); o.y = f2b(v.y); o.z = f2b(v.z); o.w = f2b(v.w);
    }
    *(ushort4*)(A + (size_t)i * NF + k) = o;
  }
}

// ---------------- WaT[f,k] = bf16(Wa[k,f]) ----------------
__global__ __launch_bounds__(256) void k_wat(const float* __restrict__ Wa,
                                             u16* __restrict__ WaT) {
  __shared__ float tile[64][65];
  int k0 = blockIdx.x * 64, f0 = blockIdx.y * 64;
  int tid = threadIdx.x;
  int col4 = (tid & 15) * 4, row = tid >> 4;
#pragma unroll
  for (int rr = 0; rr < 64; rr += 16) {
    float4 v = *(const float4*)(Wa + (size_t)(k0 + row + rr) * NF + f0 + col4);
    tile[row + rr][col4 + 0] = v.x; tile[row + rr][col4 + 1] = v.y;
    tile[row + rr][col4 + 2] = v.z; tile[row + rr][col4 + 3] = v.w;
  }
  __syncthreads();
#pragma unroll
  for (int rr = 0; rr < 64; rr += 16) {
    int f = f0 + row + rr;
    ushort4 o;
    o.x = f2b(tile[col4 + 0][row + rr]); o.y = f2b(tile[col4 + 1][row + rr]);
    o.z = f2b(tile[col4 + 2][row + rr]); o.w = f2b(tile[col4 + 3][row + rr]);
    *(ushort4*)(WaT + (size_t)f * NF + k0 + col4) = o;
  }
}

// ---------------- main GEMM: 256x256, 8-phase, barrier per phase-PAIR ----
#define LDSOFF(row, gg) ((row) * 32 + ((((gg) ^ (((row) >> 1) & 3))) << 3))

#define LDB4(BUF, KS)                                                        \
  _Pragma("unroll") for (int nf = 0; nf < 4; ++nf) {                         \
    int rb = wc * 64 + nf * 16 + lr;                                         \
    bfr[nf] = *(const bf16x8*)&lds[BUF][1][KS][LDSOFF(rb, g)];               \
  }

#define LDA4(BUF, KS, MH)                                                    \
  _Pragma("unroll") for (int mf = 0; mf < 4; ++mf) {                         \
    int ra = wr * 128 + ((MH) * 4 + mf) * 16 + lr;                           \
    afr[mf] = *(const bf16x8*)&lds[BUF][0][KS][LDSOFF(ra, g)];               \
  }

#define MFMA16(MH)                                                           \
  _Pragma("unroll") for (int mf = 0; mf < 4; ++mf)                           \
  _Pragma("unroll") for (int nf = 0; nf < 4; ++nf)                           \
    acc[(MH) * 4 + mf][nf] = __builtin_amdgcn_mfma_f32_16x16x32_bf16(        \
        afr[mf], bfr[nf], acc[(MH) * 4 + mf][nf], 0, 0, 0);

#define STAGE(SMAT, SBUF, SKS, SKT)                                          \
  if ((SKT) < NKT) {                                                         \
    _Pragma("unroll") for (int q = 0; q < 2; ++q) {                          \
      const u16* src = ((SMAT) ? pB[q] : pA[q]) + (SKT) * 64 + (SKS) * 32;   \
      ASYNC_CP16(src, &lds[SBUF][SMAT][SKS][q * 4096 + wid * 512]);          \
    }                                                                        \
  }

// BAR: 0 = no barrier (odd phase), 1 = barrier, 2 = vmcnt(4)+barrier.
#define PH(BUF, KS, MH, SMAT, SBUF, SKS, SKT, BAR)                           \
  {                                                                          \
    if ((MH) == 0) { LDB4(BUF, KS) }                                         \
    LDA4(BUF, KS, MH)                                                        \
    STAGE(SMAT, SBUF, SKS, SKT)                                              \
    __builtin_amdgcn_s_setprio(1);                                           \
    MFMA16(MH)                                                               \
    __builtin_amdgcn_s_setprio(0);                                           \
    if ((BAR) == 2) asm volatile("s_waitcnt vmcnt(4)" ::: "memory");         \
    if (BAR) __builtin_amdgcn_s_barrier();                                   \
  }

__global__ __launch_bounds__(512, 2) void k_gemm(const u16* __restrict__ A,
                                                 const u16* __restrict__ Wt,
                                                 const float* __restrict__ base,
                                                 const int* __restrict__ rowmap,
                                                 const int* __restrict__ meta,
                                                 __half* __restrict__ P,
                                                 float* __restrict__ Dpart) {
  __shared__ __align__(16) u16 lds[2][2][2][8192];   // 128 KB
  const int MT   = meta[1] >> 8;
  const int nact = MT * 12;
  const int flat = blockIdx.x;
  if (flat >= nact) return;
  const int qx = nact >> 3, rx = nact & 7;
  const int xcd = flat & 7, idx = flat >> 3;
  const int swz = (xcd < rx) ? xcd * (qx + 1) + idx
                             : rx * (qx + 1) + (xcd - rx) * qx + idx;
  const int mt = swz / 12, nt = swz - mt * 12;
  const int r0 = mt << 8, c0 = nt << 8;

  const int tid = threadIdx.x;
  const int wid = tid >> 6, lane = tid & 63;
  const int wr = wid >> 2, wc = wid & 3;
  const int g = lane >> 4, lr = lane & 15;

  const u16* pA[2]; const u16* pB[2];
#pragma unroll
  for (int q = 0; q < 2; ++q) {
    int c = q * 512 + tid;
    int row = c >> 2;
    int kc8 = (((c & 3) ^ ((row >> 1) & 3)) << 3);
    pA[q] = A  + (size_t)(r0 + row) * NF + kc8;
    pB[q] = Wt + (size_t)(c0 + row) * NF + kc8;
  }

  f32x4 acc[8][4] = {};
  bf16x8 afr[4], bfr[4];

  // prologue: kt0 complete + kt1 K-half0 (12 loads); certify all of kt0.
  STAGE(0, 0, 0, 0) STAGE(1, 0, 0, 0)
  STAGE(0, 0, 1, 0) STAGE(1, 0, 1, 0)
  STAGE(0, 1, 0, 1) STAGE(1, 1, 0, 1)
  asm volatile("s_waitcnt vmcnt(4)" ::: "memory");
  __builtin_amdgcn_s_barrier();

  // 8 phases / 2 K-tiles; barriers after even phases only.
  // Unsynced pairs have disjoint read/stage buffers:
  //  (ph1,2) read b0ks0 / stage b1ks1 ; (ph3,4) read b0ks1 / stage b0ks0
  //  (ph5,6) read b1ks0 / stage b0ks1 ; (ph7,8) read b1ks1 / stage b1ks0
#pragma unroll 1
  for (int i = 0; i < NKT / 2; ++i) {
    const int kt1 = 2 * i + 1, kt2 = 2 * i + 2, kt3 = 2 * i + 3;
    PH(0, 0, 0, 0, 1, 1, kt1, 0)
    PH(0, 0, 1, 1, 1, 1, kt1, 1)
    PH(0, 1, 0, 0, 0, 0, kt2, 0)
    PH(0, 1, 1, 1, 0, 0, kt2, 2)
    PH(1, 0, 0, 0, 0, 1, kt2, 0)
    PH(1, 0, 1, 1, 0, 1, kt2, 1)
    PH(1, 1, 0, 0, 1, 0, kt3, 0)
    PH(1, 1, 1, 1, 1, 0, kt3, 2)
  }

  // epilogue: z = acc + base; P = exp(tanh(z)); Dpart rowsums
  const int cbase = c0 + wc * 64;
#pragma unroll
  for (int mf = 0; mf < 8; ++mf) {
#pragma unroll
    for (int j = 0; j < 4; ++j) {
      int i = r0 + wr * 128 + mf * 16 + g * 4 + j;
      int b = rowmap[i] >> 9;
      float rs = 0.f;
#pragma unroll
      for (int nf = 0; nf < 4; ++nf) {
        int ccn = cbase + nf * 16 + lr;
        float z  = acc[mf][nf][j] + base[b * NF + ccn];
        z        = fminf(fmaxf(z, -15.f), 15.f);
        float e2 = __expf(2.f * z);
        float th = (e2 - 1.f) / (e2 + 1.f);
        float p  = __expf(th);
        P[(size_t)i * NF + ccn] = __float2half(p);
        rs += p;
      }
#pragma unroll
      for (int off = 1; off < 16; off <<= 1) rs += __shfl_xor(rs, off, 64);
      if (lr == 0) Dpart[(size_t)i * NDB + (cbase >> 6)] = rs;
    }
  }
}

// ---------------- invD[i] = 1 / sum_nb Dpart[i,nb] ----------------
__global__ __launch_bounds__(256) void k_invd(const float* __restrict__ Dpart,
                                              const int* __restrict__ meta,
                                              float* __restrict__ invD) {
  int i = blockIdx.x * 256 + threadIdx.x;
  if (i >= meta[1]) return;
  float d = 0.f;
#pragma unroll
  for (int q = 0; q < NDB; ++q) d += Dpart[(size_t)i * NDB + q];
  invD[i] = 1.0f / d;
}

// ---------------- final pass 1: per-(batch,chunk) partial sums ----------
__global__ __launch_bounds__(256) void k_final1(const __half* __restrict__ P,
                                                const float* __restrict__ invD,
                                                const int* __restrict__ boff,
                                                const int* __restrict__ bcnt,
                                                float* __restrict__ pb) {
  int c = blockIdx.x;                                // b*NCH + j
  int b = c >> 3, j = c & 7;
  int f = blockIdx.y * 512 + threadIdx.x * 2;
  int cnt = bcnt[b];
  int lo = j * 64, hi = min(cnt, lo + 64);
  int off = boff[b];
  __shared__ float ivs[64];
  if (threadIdx.x < 64 && lo + (int)threadIdx.x < hi)
    ivs[threadIdx.x] = invD[off + lo + threadIdx.x];
  __syncthreads();
  float ax = 0.f, ay = 0.f;
  for (int t = lo; t < hi; ++t) {
    __half2 hv = *(const __half2*)(P + (size_t)(off + t) * NF + f);
    float2 fv = __half22float2(hv);
    float iv = ivs[t - lo];
    ax += fv.x * iv; ay += fv.y * iv;
  }
  float2 o; o.x = ax; o.y = ay;
  *(float2*)(pb + (size_t)c * NF + f) = o;
}

// ---------------- final pass 2: combine + uniform + trigger mult ---------
__global__ __launch_bounds__(256) void k_final2(const float* __restrict__ pb,
                                                const int* __restrict__ bcnt,
                                                const float* __restrict__ h,
                                                const float* __restrict__ x,
                                                const int* __restrict__ trig,
                                                float* __restrict__ out) {
  int b = blockIdx.x;
  int f = blockIdx.y * 256 + threadIdx.x;
  float acc = 0.f;
#pragma unroll
  for (int j = 0; j < NCH; ++j) acc += pb[(size_t)(b * NCH + j) * NF + f];
  acc += (float)(NS - bcnt[b]) * (1.0f / (float)NF);
  int tr = trig[b];
  float ta = (f < KH) ? h[((size_t)b * NS + tr) * KH + f]
                      : x[((size_t)b * NS + tr) * SIN + f - KH];
  out[b * NF + f] = acc * ta;
}

extern "C" void kernel_launch(void* const* d_in, const int* in_sizes, int n_in,
                              void* d_out, int out_size, void* d_ws, size_t ws_size,
                              hipStream_t stream) {
  const float* h_state = (const float*)d_in[0];
  const float* x       = (const float*)d_in[1];
  const int*   trigger = (const int*)d_in[2];
  const int*   mask    = (const int*)d_in[3];
  const float* Wa      = (const float*)d_in[4];
  const float* ba      = (const float*)d_in[5];
  const float* Ws      = (const float*)d_in[6];
  const float* bs      = (const float*)d_in[7];
  float*       out     = (float*)d_out;

  // workspace layout (bytes), total ~224 MB
  char* w = (char*)d_ws;
  u16*    Abf   = (u16*)w;                 w += (size_t)NM * NF * 2;
  u16*    WaT   = (u16*)w;                 w += (size_t)NF * NF * 2;
  __half* P     = (__half*)w;              w += (size_t)NM * NF * 2;
  float*  s     = (float*)w;               w += (size_t)NBAT * KH * 4;
  float*  base  = (float*)w;               w += (size_t)NBAT * NF * 4;
  float*  Dpart = (float*)w;               w += (size_t)NM * NDB * 4;
  float*  basep = (float*)Dpart;           // alias (read before k_gemm writes)
  float*  pb    = (float*)Dpart;           // alias (written after k_invd reads)
  float*  invD  = (float*)w;               w += (size_t)NM * 4;
  int*    rowmap= (int*)w;                 w += (size_t)NM * 4;
  int*    bcnt  = (int*)w;                 w += 128;
  int*    boff  = (int*)w;                 w += 128;
  int*    meta  = (int*)w;                 w += 128;

  (void)in_sizes; (void)n_in; (void)out_size; (void)ws_size;

  k_prep  <<<dim3(1), 256, 0, stream>>>(mask, bcnt, boff, meta);
  k_gather<<<dim3(NBAT), 512, 0, stream>>>(mask, boff, meta, rowmap);
  k_sum_h <<<dim3(NBAT, 2), 256, 0, stream>>>(h_state, s);
  k_cvt_a <<<dim3(2048), 256, 0, stream>>>(h_state, x, rowmap, meta, Abf);
  k_wat   <<<dim3(NF / 64, NF / 64), 256, 0, stream>>>(Wa, WaT);
  k_base1 <<<dim3(NF / 256, KC), 256, 0, stream>>>(s, Ws, basep);
  k_base2 <<<dim3(NBAT, NF / 256), 256, 0, stream>>>(basep, ba, bs, base);
  k_gemm  <<<dim3((NF / 256) * (NM / 256)), 512, 0, stream>>>(Abf, WaT, base, rowmap, meta, P, Dpart);
  k_invd  <<<dim3(NM / 256), 256, 0, stream>>>(Dpart, meta, invD);
  k_final1<<<dim3(NBAT * NCH, NF / 512), 256, 0, stream>>>(P, invD, boff, bcnt, pb);
  k_final2<<<dim3(NBAT, NF / 256), 256, 0, stream>>>(pb, bcnt, h_state, x, trigger, out);
}

// Round 14
// 392.556 us; speedup vs baseline: 1.0855x; 1.0855x over previous
//
#include <hip/hip_runtime.h>
#include <hip/hip_bf16.h>
#include <hip/hip_fp16.h>

// Decoder_22273700397282 on MI355X (gfx950)
// out[b,f] = trigger_a[b,f] * sum_t softmax_f(tanh(a@Wa + ba + s@Ws + bs))[t,f]
// mask==0 rows -> exactly 1/3072 per feature (handled analytically).
//
// R14: merge of the two proven-best halves:
//  - non-GEMM pipeline = R12 exactly (scalar k_sum_h, 256 blocks — R13's
//    float4 version shrank the grid to 64 blocks and cost ~+60us).
//  - k_gemm = R13 exactly (barrier per phase-PAIR: 4 barriers / 2 K-tiles;
//    measured 193us, MfmaUtil 36.8%, conflicts 0).

namespace {
constexpr int SIN  = 1024;            // IN_SIZE
constexpr int KH   = 2048;            // 2*IN
constexpr int NF   = 3072;            // 3*IN = GEMM K and N
constexpr int NBAT = 32;
constexpr int NS   = 512;
constexpr int NM   = NBAT * NS;       // 16384 worst-case GEMM rows
constexpr int NDB  = NF / 64;         // 48 Dpart column blocks
constexpr int KC   = 8;               // k-chunks for k_base1
constexpr int NKT  = NF / 64;         // 48 K-tiles of 64
constexpr int NCH  = 8;               // 64-row chunks per batch
}

typedef unsigned short u16;
typedef __bf16 bf16x8 __attribute__((ext_vector_type(8)));
typedef float  f32x4  __attribute__((ext_vector_type(4)));

#define ASYNC_CP16(gptr, lptr)                                                              \
  __builtin_amdgcn_global_load_lds((__attribute__((address_space(1))) void*)(gptr),         \
                                   (__attribute__((address_space(3))) void*)(lptr), 16, 0, 0)

__device__ __forceinline__ u16 f2b(float f) {
  union { float f; unsigned u; } v; v.f = f;
  unsigned u = v.u;
  u += 0x7FFFu + ((u >> 16) & 1u);     // round-to-nearest-even
  return (u16)(u >> 16);
}

// ---------------- prep: per-batch counts + scan + meta (one block) -------
__global__ __launch_bounds__(256) void k_prep(const int* __restrict__ mask,
                                              int* __restrict__ bcnt,
                                              int* __restrict__ boff,
                                              int* __restrict__ meta) {
  int tid = threadIdx.x;
  int b = tid >> 3, seg = tid & 7;                 // 8 threads per batch
  int c = 0;
#pragma unroll
  for (int i = 0; i < 64; ++i) c += mask[b * NS + seg * 64 + i];
  c += __shfl_xor(c, 1, 64);
  c += __shfl_xor(c, 2, 64);
  c += __shfl_xor(c, 4, 64);                       // 8-lane group total
  __shared__ int sc[NBAT];
  if (seg == 0) { sc[b] = c; bcnt[b] = c; }
  __syncthreads();
  if (tid == 0) {
    int run = 0;
    for (int bb = 0; bb < NBAT; ++bb) { boff[bb] = run; run += sc[bb]; }
    meta[0] = run;                       // Mc
    meta[1] = (run + 255) & ~255;        // McPad (256-row tiles)
  }
}

// ---------------- compaction: gather ----------------
__global__ __launch_bounds__(512) void k_gather(const int* __restrict__ mask,
                                                const int* __restrict__ boff,
                                                const int* __restrict__ meta,
                                                int* __restrict__ rowmap) {
  __shared__ int ps[NS];
  int b = blockIdx.x, t = threadIdx.x;
  int m = mask[b * NS + t];
  ps[t] = m;
  __syncthreads();
#pragma unroll
  for (int off = 1; off < NS; off <<= 1) {
    int v = (t >= off) ? ps[t - off] : 0;
    __syncthreads();
    ps[t] += v;
    __syncthreads();
  }
  if (m) rowmap[boff[b] + ps[t] - m] = b * NS + t;
  if (b == 0) {                          // zero-pad rowmap up to McPad
    int Mc = meta[0], McPad = meta[1];
    if (Mc + t < McPad) rowmap[Mc + t] = 0;
  }
}

// ---------------- s[b,k] = sum_t h[b,t,k] ----------------
__global__ __launch_bounds__(256) void k_sum_h(const float* __restrict__ h,
                                               float* __restrict__ s) {
  int b = blockIdx.x;
  int d = blockIdx.y * 256 + threadIdx.x;
  const float* p = h + (size_t)b * NS * KH + d;
  float acc = 0.f;
#pragma unroll 8
  for (int t = 0; t < NS; ++t) acc += p[(size_t)t * KH];
  s[b * KH + d] = acc;
}

// ---------------- base partials: reads Ws once; float4 LDS reads ---------
__global__ __launch_bounds__(256) void k_base1(const float* __restrict__ s,
                                               const float* __restrict__ Ws,
                                               float* __restrict__ basep) {
  __shared__ float sT[NBAT][KH / KC];      // [32][256] = 32 KB
  int f  = blockIdx.x * 256 + threadIdx.x;
  int k0 = blockIdx.y * (KH / KC);
  for (int it = 0; it < NBAT; ++it) {
    int idx = it * 256 + threadIdx.x;
    int b = idx >> 8, kk = idx & 255;
    sT[b][kk] = s[b * KH + k0 + kk];
  }
  __syncthreads();
  float acc[NBAT] = {};
  for (int k = 0; k < KH / KC; k += 4) {
    float w0 = Ws[(size_t)(k0 + k + 0) * NF + f];
    float w1 = Ws[(size_t)(k0 + k + 1) * NF + f];
    float w2 = Ws[(size_t)(k0 + k + 2) * NF + f];
    float w3 = Ws[(size_t)(k0 + k + 3) * NF + f];
#pragma unroll
    for (int b = 0; b < NBAT; ++b) {
      float4 sv = *(const float4*)&sT[b][k];
      acc[b] += sv.x * w0 + sv.y * w1 + sv.z * w2 + sv.w * w3;
    }
  }
#pragma unroll
  for (int b = 0; b < NBAT; ++b)
    basep[((size_t)blockIdx.y * NBAT + b) * NF + f] = acc[b];
}

__global__ __launch_bounds__(256) void k_base2(const float* __restrict__ basep,
                                               const float* __restrict__ ba,
                                               const float* __restrict__ bs,
                                               float* __restrict__ base) {
  int b = blockIdx.x;
  int f = blockIdx.y * 256 + threadIdx.x;
  float acc = 0.f;
#pragma unroll
  for (int kc = 0; kc < KC; ++kc) acc += basep[((size_t)kc * NBAT + b) * NF + f];
  base[b * NF + f] = acc + ba[f] + bs[f];
}

// ---------------- Abf[i,k] = bf16(concat(h,x)[rowmap[i],k]) --------------
__global__ __launch_bounds__(256) void k_cvt_a(const float* __restrict__ h,
                                               const float* __restrict__ x,
                                               const int* __restrict__ rowmap,
                                               const int* __restrict__ meta,
                                               u16* __restrict__ A) {
  const int total = meta[1] * (NF / 4);
  for (int idx = blockIdx.x * 256 + threadIdx.x; idx < total;
       idx += gridDim.x * 256) {
    int i = idx / (NF / 4);
    int k = (idx - i * (NF / 4)) * 4;
    ushort4 o;
    if (i >= meta[0]) {
      o.x = o.y = o.z = o.w = 0;
    } else {
      int ro = rowmap[i];
      int b = ro >> 9, t = ro & 511;
      const float* src = (k < KH) ? h + ((size_t)b * NS + t) * KH + k
                                  : x + ((size_t)b * NS + t) * SIN + (k - KH);
      float4 v = *(const float4*)src;
      o.x = f2b(v.x); o.y = f2b(v.y); o.z = f2b(v.z); o.w = f2b(v.w);
    }
    *(ushort4*)(A + (size_t)i * NF + k) = o;
  }
}

// ---------------- WaT[f,k] = bf16(Wa[k,f]) ----------------
__global__ __launch_bounds__(256) void k_wat(const float* __restrict__ Wa,
                                             u16* __restrict__ WaT) {
  __shared__ float tile[64][65];
  int k0 = blockIdx.x * 64, f0 = blockIdx.y * 64;
  int tid = threadIdx.x;
  int col4 = (tid & 15) * 4, row = tid >> 4;
#pragma unroll
  for (int rr = 0; rr < 64; rr += 16) {
    float4 v = *(const float4*)(Wa + (size_t)(k0 + row + rr) * NF + f0 + col4);
    tile[row + rr][col4 + 0] = v.x; tile[row + rr][col4 + 1] = v.y;
    tile[row + rr][col4 + 2] = v.z; tile[row + rr][col4 + 3] = v.w;
  }
  __syncthreads();
#pragma unroll
  for (int rr = 0; rr < 64; rr += 16) {
    int f = f0 + row + rr;
    ushort4 o;
    o.x = f2b(tile[col4 + 0][row + rr]); o.y = f2b(tile[col4 + 1][row + rr]);
    o.z = f2b(tile[col4 + 2][row + rr]); o.w = f2b(tile[col4 + 3][row + rr]);
    *(ushort4*)(WaT + (size_t)f * NF + k0 + col4) = o;
  }
}

// ---------------- main GEMM: 256x256, 8-phase, barrier per phase-PAIR ----
#define LDSOFF(row, gg) ((row) * 32 + ((((gg) ^ (((row) >> 1) & 3))) << 3))

#define LDB4(BUF, KS)                                                        \
  _Pragma("unroll") for (int nf = 0; nf < 4; ++nf) {                         \
    int rb = wc * 64 + nf * 16 + lr;                                         \
    bfr[nf] = *(const bf16x8*)&lds[BUF][1][KS][LDSOFF(rb, g)];               \
  }

#define LDA4(BUF, KS, MH)                                                    \
  _Pragma("unroll") for (int mf = 0; mf < 4; ++mf) {                         \
    int ra = wr * 128 + ((MH) * 4 + mf) * 16 + lr;                           \
    afr[mf] = *(const bf16x8*)&lds[BUF][0][KS][LDSOFF(ra, g)];               \
  }

#define MFMA16(MH)                                                           \
  _Pragma("unroll") for (int mf = 0; mf < 4; ++mf)                           \
  _Pragma("unroll") for (int nf = 0; nf < 4; ++nf)                           \
    acc[(MH) * 4 + mf][nf] = __builtin_amdgcn_mfma_f32_16x16x32_bf16(        \
        afr[mf], bfr[nf], acc[(MH) * 4 + mf][nf], 0, 0, 0);

#define STAGE(SMAT, SBUF, SKS, SKT)                                          \
  if ((SKT) < NKT) {                                                         \
    _Pragma("unroll") for (int q = 0; q < 2; ++q) {                          \
      const u16* src = ((SMAT) ? pB[q] : pA[q]) + (SKT) * 64 + (SKS) * 32;   \
      ASYNC_CP16(src, &lds[SBUF][SMAT][SKS][q * 4096 + wid * 512]);          \
    }                                                                        \
  }

// BAR: 0 = no barrier (odd phase), 1 = barrier, 2 = vmcnt(4)+barrier.
#define PH(BUF, KS, MH, SMAT, SBUF, SKS, SKT, BAR)                           \
  {                                                                          \
    if ((MH) == 0) { LDB4(BUF, KS) }                                         \
    LDA4(BUF, KS, MH)                                                        \
    STAGE(SMAT, SBUF, SKS, SKT)                                              \
    __builtin_amdgcn_s_setprio(1);                                           \
    MFMA16(MH)                                                               \
    __builtin_amdgcn_s_setprio(0);                                           \
    if ((BAR) == 2) asm volatile("s_waitcnt vmcnt(4)" ::: "memory");         \
    if (BAR) __builtin_amdgcn_s_barrier();                                   \
  }

__global__ __launch_bounds__(512, 2) void k_gemm(const u16* __restrict__ A,
                                                 const u16* __restrict__ Wt,
                                                 const float* __restrict__ base,
                                                 const int* __restrict__ rowmap,
                                                 const int* __restrict__ meta,
                                                 __half* __restrict__ P,
                                                 float* __restrict__ Dpart) {
  __shared__ __align__(16) u16 lds[2][2][2][8192];   // 128 KB
  const int MT   = meta[1] >> 8;
  const int nact = MT * 12;
  const int flat = blockIdx.x;
  if (flat >= nact) return;
  const int qx = nact >> 3, rx = nact & 7;
  const int xcd = flat & 7, idx = flat >> 3;
  const int swz = (xcd < rx) ? xcd * (qx + 1) + idx
                             : rx * (qx + 1) + (xcd - rx) * qx + idx;
  const int mt = swz / 12, nt = swz - mt * 12;
  const int r0 = mt << 8, c0 = nt << 8;

  const int tid = threadIdx.x;
  const int wid = tid >> 6, lane = tid & 63;
  const int wr = wid >> 2, wc = wid & 3;
  const int g = lane >> 4, lr = lane & 15;

  const u16* pA[2]; const u16* pB[2];
#pragma unroll
  for (int q = 0; q < 2; ++q) {
    int c = q * 512 + tid;
    int row = c >> 2;
    int kc8 = (((c & 3) ^ ((row >> 1) & 3)) << 3);
    pA[q] = A  + (size_t)(r0 + row) * NF + kc8;
    pB[q] = Wt + (size_t)(c0 + row) * NF + kc8;
  }

  f32x4 acc[8][4] = {};
  bf16x8 afr[4], bfr[4];

  // prologue: kt0 complete + kt1 K-half0 (12 loads); certify all of kt0.
  STAGE(0, 0, 0, 0) STAGE(1, 0, 0, 0)
  STAGE(0, 0, 1, 0) STAGE(1, 0, 1, 0)
  STAGE(0, 1, 0, 1) STAGE(1, 1, 0, 1)
  asm volatile("s_waitcnt vmcnt(4)" ::: "memory");
  __builtin_amdgcn_s_barrier();

  // 8 phases / 2 K-tiles; barriers after even phases only.
  // Unsynced pairs have disjoint read/stage buffers:
  //  (ph1,2) read b0ks0 / stage b1ks1 ; (ph3,4) read b0ks1 / stage b0ks0
  //  (ph5,6) read b1ks0 / stage b0ks1 ; (ph7,8) read b1ks1 / stage b1ks0
#pragma unroll 1
  for (int i = 0; i < NKT / 2; ++i) {
    const int kt1 = 2 * i + 1, kt2 = 2 * i + 2, kt3 = 2 * i + 3;
    PH(0, 0, 0, 0, 1, 1, kt1, 0)
    PH(0, 0, 1, 1, 1, 1, kt1, 1)
    PH(0, 1, 0, 0, 0, 0, kt2, 0)
    PH(0, 1, 1, 1, 0, 0, kt2, 2)
    PH(1, 0, 0, 0, 0, 1, kt2, 0)
    PH(1, 0, 1, 1, 0, 1, kt2, 1)
    PH(1, 1, 0, 0, 1, 0, kt3, 0)
    PH(1, 1, 1, 1, 1, 0, kt3, 2)
  }

  // epilogue: z = acc + base; P = exp(tanh(z)); Dpart rowsums
  const int cbase = c0 + wc * 64;
#pragma unroll
  for (int mf = 0; mf < 8; ++mf) {
#pragma unroll
    for (int j = 0; j < 4; ++j) {
      int i = r0 + wr * 128 + mf * 16 + g * 4 + j;
      int b = rowmap[i] >> 9;
      float rs = 0.f;
#pragma unroll
      for (int nf = 0; nf < 4; ++nf) {
        int ccn = cbase + nf * 16 + lr;
        float z  = acc[mf][nf][j] + base[b * NF + ccn];
        z        = fminf(fmaxf(z, -15.f), 15.f);
        float e2 = __expf(2.f * z);
        float th = (e2 - 1.f) / (e2 + 1.f);
        float p  = __expf(th);
        P[(size_t)i * NF + ccn] = __float2half(p);
        rs += p;
      }
#pragma unroll
      for (int off = 1; off < 16; off <<= 1) rs += __shfl_xor(rs, off, 64);
      if (lr == 0) Dpart[(size_t)i * NDB + (cbase >> 6)] = rs;
    }
  }
}

// ---------------- invD[i] = 1 / sum_nb Dpart[i,nb] ----------------
__global__ __launch_bounds__(256) void k_invd(const float* __restrict__ Dpart,
                                              const int* __restrict__ meta,
                                              float* __restrict__ invD) {
  int i = blockIdx.x * 256 + threadIdx.x;
  if (i >= meta[1]) return;
  float d = 0.f;
#pragma unroll
  for (int q = 0; q < NDB; ++q) d += Dpart[(size_t)i * NDB + q];
  invD[i] = 1.0f / d;
}

// ---------------- final pass 1: per-(batch,chunk) partial sums ----------
__global__ __launch_bounds__(256) void k_final1(const __half* __restrict__ P,
                                                const float* __restrict__ invD,
                                                const int* __restrict__ boff,
                                                const int* __restrict__ bcnt,
                                                float* __restrict__ pb) {
  int c = blockIdx.x;                                // b*NCH + j
  int b = c >> 3, j = c & 7;
  int f = blockIdx.y * 512 + threadIdx.x * 2;
  int cnt = bcnt[b];
  int lo = j * 64, hi = min(cnt, lo + 64);
  int off = boff[b];
  __shared__ float ivs[64];
  if (threadIdx.x < 64 && lo + (int)threadIdx.x < hi)
    ivs[threadIdx.x] = invD[off + lo + threadIdx.x];
  __syncthreads();
  float ax = 0.f, ay = 0.f;
  for (int t = lo; t < hi; ++t) {
    __half2 hv = *(const __half2*)(P + (size_t)(off + t) * NF + f);
    float2 fv = __half22float2(hv);
    float iv = ivs[t - lo];
    ax += fv.x * iv; ay += fv.y * iv;
  }
  float2 o; o.x = ax; o.y = ay;
  *(float2*)(pb + (size_t)c * NF + f) = o;
}

// ---------------- final pass 2: combine + uniform + trigger mult ---------
__global__ __launch_bounds__(256) void k_final2(const float* __restrict__ pb,
                                                const int* __restrict__ bcnt,
                                                const float* __restrict__ h,
                                                const float* __restrict__ x,
                                                const int* __restrict__ trig,
                                                float* __restrict__ out) {
  int b = blockIdx.x;
  int f = blockIdx.y * 256 + threadIdx.x;
  float acc = 0.f;
#pragma unroll
  for (int j = 0; j < NCH; ++j) acc += pb[(size_t)(b * NCH + j) * NF + f];
  acc += (float)(NS - bcnt[b]) * (1.0f / (float)NF);
  int tr = trig[b];
  float ta = (f < KH) ? h[((size_t)b * NS + tr) * KH + f]
                      : x[((size_t)b * NS + tr) * SIN + f - KH];
  out[b * NF + f] = acc * ta;
}

extern "C" void kernel_launch(void* const* d_in, const int* in_sizes, int n_in,
                              void* d_out, int out_size, void* d_ws, size_t ws_size,
                              hipStream_t stream) {
  const float* h_state = (const float*)d_in[0];
  const float* x       = (const float*)d_in[1];
  const int*   trigger = (const int*)d_in[2];
  const int*   mask    = (const int*)d_in[3];
  const float* Wa      = (const float*)d_in[4];
  const float* ba      = (const float*)d_in[5];
  const float* Ws      = (const float*)d_in[6];
  const float* bs      = (const float*)d_in[7];
  float*       out     = (float*)d_out;

  // workspace layout (bytes), total ~224 MB
  char* w = (char*)d_ws;
  u16*    Abf   = (u16*)w;                 w += (size_t)NM * NF * 2;
  u16*    WaT   = (u16*)w;                 w += (size_t)NF * NF * 2;
  __half* P     = (__half*)w;              w += (size_t)NM * NF * 2;
  float*  s     = (float*)w;               w += (size_t)NBAT * KH * 4;
  float*  base  = (float*)w;               w += (size_t)NBAT * NF * 4;
  float*  Dpart = (float*)w;               w += (size_t)NM * NDB * 4;
  float*  basep = (float*)Dpart;           // alias (read before k_gemm writes)
  float*  pb    = (float*)Dpart;           // alias (written after k_invd reads)
  float*  invD  = (float*)w;               w += (size_t)NM * 4;
  int*    rowmap= (int*)w;                 w += (size_t)NM * 4;
  int*    bcnt  = (int*)w;                 w += 128;
  int*    boff  = (int*)w;                 w += 128;
  int*    meta  = (int*)w;                 w += 128;

  (void)in_sizes; (void)n_in; (void)out_size; (void)ws_size;

  k_prep  <<<dim3(1), 256, 0, stream>>>(mask, bcnt, boff, meta);
  k_gather<<<dim3(NBAT), 512, 0, stream>>>(mask, boff, meta, rowmap);
  k_sum_h <<<dim3(NBAT, KH / 256), 256, 0, stream>>>(h_state, s);
  k_cvt_a <<<dim3(2048), 256, 0, stream>>>(h_state, x, rowmap, meta, Abf);
  k_wat   <<<dim3(NF / 64, NF / 64), 256, 0, stream>>>(Wa, WaT);
  k_base1 <<<dim3(NF / 256, KC), 256, 0, stream>>>(s, Ws, basep);
  k_base2 <<<dim3(NBAT, NF / 256), 256, 0, stream>>>(basep, ba, bs, base);
  k_gemm  <<<dim3((NF / 256) * (NM / 256)), 512, 0, stream>>>(Abf, WaT, base, rowmap, meta, P, Dpart);
  k_invd  <<<dim3(NM / 256), 256, 0, stream>>>(Dpart, meta, invD);
  k_final1<<<dim3(NBAT * NCH, NF / 512), 256, 0, stream>>>(P, invD, boff, bcnt, pb);
  k_final2<<<dim3(NBAT, NF / 256), 256, 0, stream>>>(pb, bcnt, h_state, x, trigger, out);
}

// Round 15
// 389.501 us; speedup vs baseline: 1.0941x; 1.0078x over previous
//
#include <hip/hip_runtime.h>
#include <hip/hip_bf16.h>
#include <hip/hip_fp16.h>

// Decoder_22273700397282 on MI355X (gfx950)
// out[b,f] = trigger_a[b,f] * sum_t softmax_f(tanh(a@Wa + ba + s@Ws + bs))[t,f]
// mask==0 rows -> exactly 1/3072 per feature (handled analytically).
//
// R15 (non-GEMM only; k_gemm = R13/R14 state, 193us/36.8% MfmaUtil):
//  - k_cvt_a processes 8 cols/item (16B stores, 2x float4 loads).
//  - k_invd fused into k_final1 (per-block recompute of its 64 invD values
//    from Dpart); pb un-aliased from Dpart (would race once fused).
//  - k_final1 uses 8B half2x2 loads over 1024-col f-blocks.
//  Launches 11 -> 10.

namespace {
constexpr int SIN  = 1024;            // IN_SIZE
constexpr int KH   = 2048;            // 2*IN
constexpr int NF   = 3072;            // 3*IN = GEMM K and N
constexpr int NBAT = 32;
constexpr int NS   = 512;
constexpr int NM   = NBAT * NS;       // 16384 worst-case GEMM rows
constexpr int NDB  = NF / 64;         // 48 Dpart column blocks
constexpr int KC   = 8;               // k-chunks for k_base1
constexpr int NKT  = NF / 64;         // 48 K-tiles of 64
constexpr int NCH  = 8;               // 64-row chunks per batch
}

typedef unsigned short u16;
typedef __bf16 bf16x8 __attribute__((ext_vector_type(8)));
typedef float  f32x4  __attribute__((ext_vector_type(4)));

#define ASYNC_CP16(gptr, lptr)                                                              \
  __builtin_amdgcn_global_load_lds((__attribute__((address_space(1))) void*)(gptr),         \
                                   (__attribute__((address_space(3))) void*)(lptr), 16, 0, 0)

__device__ __forceinline__ u16 f2b(float f) {
  union { float f; unsigned u; } v; v.f = f;
  unsigned u = v.u;
  u += 0x7FFFu + ((u >> 16) & 1u);     // round-to-nearest-even
  return (u16)(u >> 16);
}

__device__ __forceinline__ unsigned pk2(float a, float b) {
  return (unsigned)f2b(a) | ((unsigned)f2b(b) << 16);
}

// ---------------- prep: per-batch counts + scan + meta (one block) -------
__global__ __launch_bounds__(256) void k_prep(const int* __restrict__ mask,
                                              int* __restrict__ bcnt,
                                              int* __restrict__ boff,
                                              int* __restrict__ meta) {
  int tid = threadIdx.x;
  int b = tid >> 3, seg = tid & 7;                 // 8 threads per batch
  int c = 0;
#pragma unroll
  for (int i = 0; i < 64; ++i) c += mask[b * NS + seg * 64 + i];
  c += __shfl_xor(c, 1, 64);
  c += __shfl_xor(c, 2, 64);
  c += __shfl_xor(c, 4, 64);                       // 8-lane group total
  __shared__ int sc[NBAT];
  if (seg == 0) { sc[b] = c; bcnt[b] = c; }
  __syncthreads();
  if (tid == 0) {
    int run = 0;
    for (int bb = 0; bb < NBAT; ++bb) { boff[bb] = run; run += sc[bb]; }
    meta[0] = run;                       // Mc
    meta[1] = (run + 255) & ~255;        // McPad (256-row tiles)
  }
}

// ---------------- compaction: gather ----------------
__global__ __launch_bounds__(512) void k_gather(const int* __restrict__ mask,
                                                const int* __restrict__ boff,
                                                const int* __restrict__ meta,
                                                int* __restrict__ rowmap) {
  __shared__ int ps[NS];
  int b = blockIdx.x, t = threadIdx.x;
  int m = mask[b * NS + t];
  ps[t] = m;
  __syncthreads();
#pragma unroll
  for (int off = 1; off < NS; off <<= 1) {
    int v = (t >= off) ? ps[t - off] : 0;
    __syncthreads();
    ps[t] += v;
    __syncthreads();
  }
  if (m) rowmap[boff[b] + ps[t] - m] = b * NS + t;
  if (b == 0) {                          // zero-pad rowmap up to McPad
    int Mc = meta[0], McPad = meta[1];
    if (Mc + t < McPad) rowmap[Mc + t] = 0;
  }
}

// ---------------- s[b,k] = sum_t h[b,t,k] ----------------
__global__ __launch_bounds__(256) void k_sum_h(const float* __restrict__ h,
                                               float* __restrict__ s) {
  int b = blockIdx.x;
  int d = blockIdx.y * 256 + threadIdx.x;
  const float* p = h + (size_t)b * NS * KH + d;
  float acc = 0.f;
#pragma unroll 8
  for (int t = 0; t < NS; ++t) acc += p[(size_t)t * KH];
  s[b * KH + d] = acc;
}

// ---------------- base partials: reads Ws once; float4 LDS reads ---------
__global__ __launch_bounds__(256) void k_base1(const float* __restrict__ s,
                                               const float* __restrict__ Ws,
                                               float* __restrict__ basep) {
  __shared__ float sT[NBAT][KH / KC];      // [32][256] = 32 KB
  int f  = blockIdx.x * 256 + threadIdx.x;
  int k0 = blockIdx.y * (KH / KC);
  for (int it = 0; it < NBAT; ++it) {
    int idx = it * 256 + threadIdx.x;
    int b = idx >> 8, kk = idx & 255;
    sT[b][kk] = s[b * KH + k0 + kk];
  }
  __syncthreads();
  float acc[NBAT] = {};
  for (int k = 0; k < KH / KC; k += 4) {
    float w0 = Ws[(size_t)(k0 + k + 0) * NF + f];
    float w1 = Ws[(size_t)(k0 + k + 1) * NF + f];
    float w2 = Ws[(size_t)(k0 + k + 2) * NF + f];
    float w3 = Ws[(size_t)(k0 + k + 3) * NF + f];
#pragma unroll
    for (int b = 0; b < NBAT; ++b) {
      float4 sv = *(const float4*)&sT[b][k];
      acc[b] += sv.x * w0 + sv.y * w1 + sv.z * w2 + sv.w * w3;
    }
  }
#pragma unroll
  for (int b = 0; b < NBAT; ++b)
    basep[((size_t)blockIdx.y * NBAT + b) * NF + f] = acc[b];
}

__global__ __launch_bounds__(256) void k_base2(const float* __restrict__ basep,
                                               const float* __restrict__ ba,
                                               const float* __restrict__ bs,
                                               float* __restrict__ base) {
  int b = blockIdx.x;
  int f = blockIdx.y * 256 + threadIdx.x;
  float acc = 0.f;
#pragma unroll
  for (int kc = 0; kc < KC; ++kc) acc += basep[((size_t)kc * NBAT + b) * NF + f];
  base[b * NF + f] = acc + ba[f] + bs[f];
}

// ---------------- Abf[i,k] = bf16(concat(h,x)[rowmap[i],k]), 8 cols/item --
__global__ __launch_bounds__(256) void k_cvt_a(const float* __restrict__ h,
                                               const float* __restrict__ x,
                                               const int* __restrict__ rowmap,
                                               const int* __restrict__ meta,
                                               u16* __restrict__ A) {
  const int total = meta[1] * (NF / 8);
  for (int idx = blockIdx.x * 256 + threadIdx.x; idx < total;
       idx += gridDim.x * 256) {
    int i = idx / (NF / 8);
    int k = (idx - i * (NF / 8)) * 8;
    uint4 o;
    if (i >= meta[0]) {
      o.x = o.y = o.z = o.w = 0u;
    } else {
      int ro = rowmap[i];
      int b = ro >> 9, t = ro & 511;
      const float* src = (k < KH) ? h + ((size_t)b * NS + t) * KH + k
                                  : x + ((size_t)b * NS + t) * SIN + (k - KH);
      float4 v0 = *(const float4*)src;
      float4 v1 = *(const float4*)(src + 4);
      o.x = pk2(v0.x, v0.y); o.y = pk2(v0.z, v0.w);
      o.z = pk2(v1.x, v1.y); o.w = pk2(v1.z, v1.w);
    }
    *(uint4*)(A + (size_t)i * NF + k) = o;
  }
}

// ---------------- WaT[f,k] = bf16(Wa[k,f]) ----------------
__global__ __launch_bounds__(256) void k_wat(const float* __restrict__ Wa,
                                             u16* __restrict__ WaT) {
  __shared__ float tile[64][65];
  int k0 = blockIdx.x * 64, f0 = blockIdx.y * 64;
  int tid = threadIdx.x;
  int col4 = (tid & 15) * 4, row = tid >> 4;
#pragma unroll
  for (int rr = 0; rr < 64; rr += 16) {
    float4 v = *(const float4*)(Wa + (size_t)(k0 + row + rr) * NF + f0 + col4);
    tile[row + rr][col4 + 0] = v.x; tile[row + rr][col4 + 1] = v.y;
    tile[row + rr][col4 + 2] = v.z; tile[row + rr][col4 + 3] = v.w;
  }
  __syncthreads();
#pragma unroll
  for (int rr = 0; rr < 64; rr += 16) {
    int f = f0 + row + rr;
    ushort4 o;
    o.x = f2b(tile[col4 + 0][row + rr]); o.y = f2b(tile[col4 + 1][row + rr]);
    o.z = f2b(tile[col4 + 2][row + rr]); o.w = f2b(tile[col4 + 3][row + rr]);
    *(ushort4*)(WaT + (size_t)f * NF + k0 + col4) = o;
  }
}

// ---------------- main GEMM: 256x256, 8-phase, barrier per phase-PAIR ----
#define LDSOFF(row, gg) ((row) * 32 + ((((gg) ^ (((row) >> 1) & 3))) << 3))

#define LDB4(BUF, KS)                                                        \
  _Pragma("unroll") for (int nf = 0; nf < 4; ++nf) {                         \
    int rb = wc * 64 + nf * 16 + lr;                                         \
    bfr[nf] = *(const bf16x8*)&lds[BUF][1][KS][LDSOFF(rb, g)];               \
  }

#define LDA4(BUF, KS, MH)                                                    \
  _Pragma("unroll") for (int mf = 0; mf < 4; ++mf) {                         \
    int ra = wr * 128 + ((MH) * 4 + mf) * 16 + lr;                           \
    afr[mf] = *(const bf16x8*)&lds[BUF][0][KS][LDSOFF(ra, g)];               \
  }

#define MFMA16(MH)                                                           \
  _Pragma("unroll") for (int mf = 0; mf < 4; ++mf)                           \
  _Pragma("unroll") for (int nf = 0; nf < 4; ++nf)                           \
    acc[(MH) * 4 + mf][nf] = __builtin_amdgcn_mfma_f32_16x16x32_bf16(        \
        afr[mf], bfr[nf], acc[(MH) * 4 + mf][nf], 0, 0, 0);

#define STAGE(SMAT, SBUF, SKS, SKT)                                          \
  if ((SKT) < NKT) {                                                         \
    _Pragma("unroll") for (int q = 0; q < 2; ++q) {                          \
      const u16* src = ((SMAT) ? pB[q] : pA[q]) + (SKT) * 64 + (SKS) * 32;   \
      ASYNC_CP16(src, &lds[SBUF][SMAT][SKS][q * 4096 + wid * 512]);          \
    }                                                                        \
  }

// BAR: 0 = no barrier (odd phase), 1 = barrier, 2 = vmcnt(4)+barrier.
#define PH(BUF, KS, MH, SMAT, SBUF, SKS, SKT, BAR)                           \
  {                                                                          \
    if ((MH) == 0) { LDB4(BUF, KS) }                                         \
    LDA4(BUF, KS, MH)                                                        \
    STAGE(SMAT, SBUF, SKS, SKT)                                              \
    __builtin_amdgcn_s_setprio(1);                                           \
    MFMA16(MH)                                                               \
    __builtin_amdgcn_s_setprio(0);                                           \
    if ((BAR) == 2) asm volatile("s_waitcnt vmcnt(4)" ::: "memory");         \
    if (BAR) __builtin_amdgcn_s_barrier();                                   \
  }

__global__ __launch_bounds__(512, 2) void k_gemm(const u16* __restrict__ A,
                                                 const u16* __restrict__ Wt,
                                                 const float* __restrict__ base,
                                                 const int* __restrict__ rowmap,
                                                 const int* __restrict__ meta,
                                                 __half* __restrict__ P,
                                                 float* __restrict__ Dpart) {
  __shared__ __align__(16) u16 lds[2][2][2][8192];   // 128 KB
  const int MT   = meta[1] >> 8;
  const int nact = MT * 12;
  const int flat = blockIdx.x;
  if (flat >= nact) return;
  const int qx = nact >> 3, rx = nact & 7;
  const int xcd = flat & 7, idx = flat >> 3;
  const int swz = (xcd < rx) ? xcd * (qx + 1) + idx
                             : rx * (qx + 1) + (xcd - rx) * qx + idx;
  const int mt = swz / 12, nt = swz - mt * 12;
  const int r0 = mt << 8, c0 = nt << 8;

  const int tid = threadIdx.x;
  const int wid = tid >> 6, lane = tid & 63;
  const int wr = wid >> 2, wc = wid & 3;
  const int g = lane >> 4, lr = lane & 15;

  const u16* pA[2]; const u16* pB[2];
#pragma unroll
  for (int q = 0; q < 2; ++q) {
    int c = q * 512 + tid;
    int row = c >> 2;
    int kc8 = (((c & 3) ^ ((row >> 1) & 3)) << 3);
    pA[q] = A  + (size_t)(r0 + row) * NF + kc8;
    pB[q] = Wt + (size_t)(c0 + row) * NF + kc8;
  }

  f32x4 acc[8][4] = {};
  bf16x8 afr[4], bfr[4];

  // prologue: kt0 complete + kt1 K-half0 (12 loads); certify all of kt0.
  STAGE(0, 0, 0, 0) STAGE(1, 0, 0, 0)
  STAGE(0, 0, 1, 0) STAGE(1, 0, 1, 0)
  STAGE(0, 1, 0, 1) STAGE(1, 1, 0, 1)
  asm volatile("s_waitcnt vmcnt(4)" ::: "memory");
  __builtin_amdgcn_s_barrier();

  // 8 phases / 2 K-tiles; barriers after even phases only.
  // Unsynced pairs have disjoint read/stage buffers:
  //  (ph1,2) read b0ks0 / stage b1ks1 ; (ph3,4) read b0ks1 / stage b0ks0
  //  (ph5,6) read b1ks0 / stage b0ks1 ; (ph7,8) read b1ks1 / stage b1ks0
#pragma unroll 1
  for (int i = 0; i < NKT / 2; ++i) {
    const int kt1 = 2 * i + 1, kt2 = 2 * i + 2, kt3 = 2 * i + 3;
    PH(0, 0, 0, 0, 1, 1, kt1, 0)
    PH(0, 0, 1, 1, 1, 1, kt1, 1)
    PH(0, 1, 0, 0, 0, 0, kt2, 0)
    PH(0, 1, 1, 1, 0, 0, kt2, 2)
    PH(1, 0, 0, 0, 0, 1, kt2, 0)
    PH(1, 0, 1, 1, 0, 1, kt2, 1)
    PH(1, 1, 0, 0, 1, 0, kt3, 0)
    PH(1, 1, 1, 1, 1, 0, kt3, 2)
  }

  // epilogue: z = acc + base; P = exp(tanh(z)); Dpart rowsums
  const int cbase = c0 + wc * 64;
#pragma unroll
  for (int mf = 0; mf < 8; ++mf) {
#pragma unroll
    for (int j = 0; j < 4; ++j) {
      int i = r0 + wr * 128 + mf * 16 + g * 4 + j;
      int b = rowmap[i] >> 9;
      float rs = 0.f;
#pragma unroll
      for (int nf = 0; nf < 4; ++nf) {
        int ccn = cbase + nf * 16 + lr;
        float z  = acc[mf][nf][j] + base[b * NF + ccn];
        z        = fminf(fmaxf(z, -15.f), 15.f);
        float e2 = __expf(2.f * z);
        float th = (e2 - 1.f) / (e2 + 1.f);
        float p  = __expf(th);
        P[(size_t)i * NF + ccn] = __float2half(p);
        rs += p;
      }
#pragma unroll
      for (int off = 1; off < 16; off <<= 1) rs += __shfl_xor(rs, off, 64);
      if (lr == 0) Dpart[(size_t)i * NDB + (cbase >> 6)] = rs;
    }
  }
}

// ---------------- final pass 1: invD (fused) + per-(batch,chunk) sums ----
// pb[(b*NCH+j)*NF + f] = sum_{t in chunk} P[off+t, f] / D[off+t]
__global__ __launch_bounds__(256) void k_final1(const __half* __restrict__ P,
                                                const float* __restrict__ Dpart,
                                                const int* __restrict__ boff,
                                                const int* __restrict__ bcnt,
                                                float* __restrict__ pb) {
  int c = blockIdx.x;                                // b*NCH + j
  int b = c >> 3, j = c & 7;
  int f = blockIdx.y * 1024 + threadIdx.x * 4;
  int cnt = bcnt[b];
  int lo = j * 64, hi = min(cnt, lo + 64);
  int off = boff[b];
  __shared__ float ivs[64];
  if (threadIdx.x < 64) {
    int t = lo + threadIdx.x;
    if (t < hi) {
      const float* dp = Dpart + (size_t)(off + t) * NDB;
      float d = 0.f;
#pragma unroll
      for (int q = 0; q < NDB; ++q) d += dp[q];
      ivs[threadIdx.x] = 1.0f / d;
    }
  }
  __syncthreads();
  float a0 = 0.f, a1 = 0.f, a2 = 0.f, a3 = 0.f;
  for (int t = lo; t < hi; ++t) {
    const __half2* hp = (const __half2*)(P + (size_t)(off + t) * NF + f);
    __half2 h0 = hp[0], h1 = hp[1];                  // 8B load
    float2 f0 = __half22float2(h0), f1 = __half22float2(h1);
    float iv = ivs[t - lo];
    a0 += f0.x * iv; a1 += f0.y * iv; a2 += f1.x * iv; a3 += f1.y * iv;
  }
  float4 o; o.x = a0; o.y = a1; o.z = a2; o.w = a3;
  *(float4*)(pb + (size_t)c * NF + f) = o;
}

// ---------------- final pass 2: combine + uniform + trigger mult ---------
__global__ __launch_bounds__(256) void k_final2(const float* __restrict__ pb,
                                                const int* __restrict__ bcnt,
                                                const float* __restrict__ h,
                                                const float* __restrict__ x,
                                                const int* __restrict__ trig,
                                                float* __restrict__ out) {
  int b = blockIdx.x;
  int f = blockIdx.y * 256 + threadIdx.x;
  float acc = 0.f;
#pragma unroll
  for (int j = 0; j < NCH; ++j) acc += pb[(size_t)(b * NCH + j) * NF + f];
  acc += (float)(NS - bcnt[b]) * (1.0f / (float)NF);
  int tr = trig[b];
  float ta = (f < KH) ? h[((size_t)b * NS + tr) * KH + f]
                      : x[((size_t)b * NS + tr) * SIN + f - KH];
  out[b * NF + f] = acc * ta;
}

extern "C" void kernel_launch(void* const* d_in, const int* in_sizes, int n_in,
                              void* d_out, int out_size, void* d_ws, size_t ws_size,
                              hipStream_t stream) {
  const float* h_state = (const float*)d_in[0];
  const float* x       = (const float*)d_in[1];
  const int*   trigger = (const int*)d_in[2];
  const int*   mask    = (const int*)d_in[3];
  const float* Wa      = (const float*)d_in[4];
  const float* ba      = (const float*)d_in[5];
  const float* Ws      = (const float*)d_in[6];
  const float* bs      = (const float*)d_in[7];
  float*       out     = (float*)d_out;

  // workspace layout (bytes), total ~228 MB
  char* w = (char*)d_ws;
  u16*    Abf   = (u16*)w;                 w += (size_t)NM * NF * 2;
  u16*    WaT   = (u16*)w;                 w += (size_t)NF * NF * 2;
  __half* P     = (__half*)w;              w += (size_t)NM * NF * 2;
  float*  s     = (float*)w;               w += (size_t)NBAT * KH * 4;
  float*  base  = (float*)w;               w += (size_t)NBAT * NF * 4;
  float*  Dpart = (float*)w;               w += (size_t)NM * NDB * 4;
  float*  basep = (float*)Dpart;           // alias (read before k_gemm writes)
  float*  pb    = (float*)w;               w += (size_t)NBAT * NCH * NF * 4;
  int*    rowmap= (int*)w;                 w += (size_t)NM * 4;
  int*    bcnt  = (int*)w;                 w += 128;
  int*    boff  = (int*)w;                 w += 128;
  int*    meta  = (int*)w;                 w += 128;

  (void)in_sizes; (void)n_in; (void)out_size; (void)ws_size;

  k_prep  <<<dim3(1), 256, 0, stream>>>(mask, bcnt, boff, meta);
  k_gather<<<dim3(NBAT), 512, 0, stream>>>(mask, boff, meta, rowmap);
  k_sum_h <<<dim3(NBAT, KH / 256), 256, 0, stream>>>(h_state, s);
  k_cvt_a <<<dim3(2048), 256, 0, stream>>>(h_state, x, rowmap, meta, Abf);
  k_wat   <<<dim3(NF / 64, NF / 64), 256, 0, stream>>>(Wa, WaT);
  k_base1 <<<dim3(NF / 256, KC), 256, 0, stream>>>(s, Ws, basep);
  k_base2 <<<dim3(NBAT, NF / 256), 256, 0, stream>>>(basep, ba, bs, base);
  k_gemm  <<<dim3((NF / 256) * (NM / 256)), 512, 0, stream>>>(Abf, WaT, base, rowmap, meta, P, Dpart);
  k_final1<<<dim3(NBAT * NCH, NF / 1024), 256, 0, stream>>>(P, Dpart, boff, bcnt, pb);
  k_final2<<<dim3(NBAT, NF / 256), 256, 0, stream>>>(pb, bcnt, h_state, x, trigger, out);
}